// Round 3
// baseline (99.530 us; speedup 1.0000x reference)
//
#include <hip/hip_runtime.h>
#include <stdint.h>

using i32x4  = __attribute__((ext_vector_type(4))) int;
using i32x16 = __attribute__((ext_vector_type(16))) int;

// ---------------- ws layout ----------------
#define WS_SCALED   2048
#define WS_SCALEF   2056
#define WS_FACT     4096
#define WS_XQ       (1u << 20)
#define WS_QW       ((1u << 20) + (32u << 20))

// ---------------- kernel 1: partial sums of |w| (deterministic) ----------------
__global__ __launch_bounds__(256) void k_wabs_partial(const float* __restrict__ w,
                                                      double* __restrict__ partials) {
    int t = threadIdx.x;
    int b = blockIdx.x;
    const float4* w4 = (const float4*)(w + b * 4096);
    double s = 0.0;
#pragma unroll
    for (int i = 0; i < 4; ++i) {
        float4 v = w4[i * 256 + t];
        s += (double)fabsf(v.x) + (double)fabsf(v.y) +
             (double)fabsf(v.z) + (double)fabsf(v.w);
    }
#pragma unroll
    for (int off = 32; off > 0; off >>= 1) s += __shfl_down(s, off, 64);
    __shared__ double lds[4];
    if ((t & 63) == 0) lds[t >> 6] = s;
    __syncthreads();
    if (t == 0) partials[b] = ((lds[0] + lds[1]) + (lds[2] + lds[3]));
}

// ---------------- kernel 2: finalize scale ----------------
__global__ __launch_bounds__(256) void k_scale(const double* __restrict__ partials,
                                               double* __restrict__ scale_d,
                                               float* __restrict__ scale_f) {
    int t = threadIdx.x;
    double s = partials[t];
#pragma unroll
    for (int off = 32; off > 0; off >>= 1) s += __shfl_down(s, off, 64);
    __shared__ double lds[4];
    if ((t & 63) == 0) lds[t >> 6] = s;
    __syncthreads();
    if (t == 0) {
        double m = ((lds[0] + lds[1]) + (lds[2] + lds[3])) / 1048576.0;
        if (m < 1e-5) m = 1e-5;
        *scale_d = m;
        *scale_f = (float)m;
    }
}

// ---------------- kernel 3: ternary weight quant ----------------
__global__ __launch_bounds__(256) void k_wquant(const float* __restrict__ w,
                                                const double* __restrict__ scale_d,
                                                int8_t* __restrict__ qw) {
    double half_s = 0.5 * (*scale_d);
    int idx = blockIdx.x * 2048 + threadIdx.x * 8;
    float4 v0 = *(const float4*)(w + idx);
    float4 v1 = *(const float4*)(w + idx + 4);
    float f[8] = {v0.x, v0.y, v0.z, v0.w, v1.x, v1.y, v1.z, v1.w};
    union { char c[8]; int2 p; } u;
#pragma unroll
    for (int i = 0; i < 8; ++i) {
        char q = 0;
        if ((double)fabsf(f[i]) > half_s) q = (f[i] > 0.0f) ? 1 : -1;
        u.c[i] = q;
    }
    *(int2*)(qw + idx) = u.p;
}

// ---------------- kernel 4: per-token int8 activation quant ----------------
__device__ inline int q8pack(float4 f, float as) {
    int a = (int)fminf(fmaxf(rintf(f.x * as), -128.0f), 127.0f);
    int b = (int)fminf(fmaxf(rintf(f.y * as), -128.0f), 127.0f);
    int c = (int)fminf(fmaxf(rintf(f.z * as), -128.0f), 127.0f);
    int d = (int)fminf(fmaxf(rintf(f.w * as), -128.0f), 127.0f);
    return (a & 0xff) | ((b & 0xff) << 8) | ((c & 0xff) << 16) | ((d & 0xff) << 24);
}

__global__ __launch_bounds__(256) void k_aquant(const float* __restrict__ x,
                                                const float* __restrict__ scale_f,
                                                int8_t* __restrict__ xq,
                                                float* __restrict__ fact) {
    int wid = threadIdx.x >> 6;
    int lane = threadIdx.x & 63;
    int token = blockIdx.x * 4 + wid;
    const float* xr = x + (size_t)token * 1024;
    float4 v[4];
    float m = 0.0f;
#pragma unroll
    for (int c = 0; c < 4; ++c) {
        v[c] = *(const float4*)(xr + c * 256 + lane * 4);
        m = fmaxf(m, fmaxf(fmaxf(fabsf(v[c].x), fabsf(v[c].y)),
                           fmaxf(fabsf(v[c].z), fabsf(v[c].w))));
    }
#pragma unroll
    for (int off = 32; off > 0; off >>= 1) m = fmaxf(m, __shfl_xor(m, off, 64));
    m = fmaxf(m, 1e-5f);
    float as = 127.0f / m;
    int* xqo = (int*)xq;
#pragma unroll
    for (int c = 0; c < 4; ++c)
        xqo[token * 256 + c * 64 + lane] = q8pack(v[c], as);
    if (lane == 0) fact[token] = (*scale_f) / as;
}

// ---------------- kernel 5: i8 MFMA GEMM, 256x256 tile, 8-phase, 32x32x32 ----------------
// BM=BN=256, BK=128. 8 waves (2M x 4N), per-wave 128x64 = 4x2 tiles of 32x32.
// Zigzag quadrants Q(mh,nh): 00 -> 01 -> 11 -> 10 with BOTH B halves held in regs
// (zero LDS re-reads: 24 ds_read_b128 / wave / K-tile).
// Staging identical to proven round-2 schedule; vmcnt(6) = exactly the 3 t+2 units.

__device__ __forceinline__ void gl_lds16(const void* g, void* l) {
    __builtin_amdgcn_global_load_lds((const __attribute__((address_space(1))) void*)g,
                                     (__attribute__((address_space(3))) void*)l, 16, 0, 0);
}

#define PH32(MH, NH, BRS) \
    __builtin_amdgcn_s_barrier(); \
    asm volatile("s_waitcnt lgkmcnt(0)" ::: "memory"); \
    __builtin_amdgcn_sched_barrier(0); \
    __builtin_amdgcn_s_setprio(1); \
    _Pragma("unroll") \
    for (int ks = 0; ks < 4; ++ks) \
    _Pragma("unroll") \
    for (int mt = 0; mt < 2; ++mt) \
        acc[MH*2+mt][NH] = __builtin_amdgcn_mfma_i32_32x32x32_i8( \
            aR[mt][ks], BRS[ks], acc[MH*2+mt][NH], 0, 0, 0); \
    __builtin_amdgcn_s_setprio(0); \
    __builtin_amdgcn_s_barrier();

__global__ __launch_bounds__(512, 2) void k_gemm3(const int8_t* __restrict__ A,
                                                  const int8_t* __restrict__ B,
                                                  const float* __restrict__ fact,
                                                  const float* __restrict__ bias,
                                                  float* __restrict__ out) {
    __shared__ int8_t As[2][256 * 128];
    __shared__ int8_t Bs[2][256 * 128];
    const int tid  = threadIdx.x;
    const int lane = tid & 63;
    const int wid  = tid >> 6;
    const int wm   = wid >> 2;     // 0..1
    const int wn   = wid & 3;      // 0..3
    const int l31  = lane & 31;
    const int l5   = lane >> 5;

    // XCD-aware swizzle (512 blocks % 8 == 0 -> bijective)
    int bid = blockIdx.x;
    int swz = (bid & 7) * 64 + (bid >> 3);
    int tm = swz >> 2;             // 0..127
    int tn = swz & 3;              // 0..3

    const int8_t* Ag = A + (size_t)tm * 256 * 1024;
    const int8_t* Bg = B + (size_t)tn * 256 * 1024;

    const int sr  = tid >> 3;      // 0..63
    const int ssl = tid & 7;       // slot 0..7

    auto stageA = [&](int bi, int r0, int kb) {
        int pr = r0 + sr;
        gl_lds16(Ag + (size_t)pr * 1024 + kb + ((ssl ^ (pr & 7)) << 4),
                 &As[bi][r0 * 128 + tid * 16]);
    };
    auto stageB = [&](int bi, int r0, int kb) {
        int pr = r0 + sr;
        int br = ((pr & 127) >> 5) * 64 + ((pr >> 7) << 5) + (pr & 31);
        gl_lds16(Bg + (size_t)br * 1024 + kb + ((ssl ^ (pr & 7)) << 4),
                 &Bs[bi][r0 * 128 + tid * 16]);
    };
    // 32x32x32 fragments: row = lane&31, 16B of K at (lane>>5)*16 within kstep*32
    auto ldA32 = [&](int bi, int mh, int mt, int ks) -> i32x4 {
        int r  = wm * 128 + mh * 64 + mt * 32 + l31;
        int sl = ((ks << 1) + l5) ^ (r & 7);
        return *(const i32x4*)&As[bi][r * 128 + (sl << 4)];
    };
    auto ldB32 = [&](int bi, int nh, int ks) -> i32x4 {
        int pr = nh * 128 + wn * 32 + l31;  // holds global col wn*64 + nh*32 + l31
        int sl = ((ks << 1) + l5) ^ (pr & 7);
        return *(const i32x4*)&Bs[bi][pr * 128 + (sl << 4)];
    };

    i32x16 acc[4][2];
#pragma unroll
    for (int i = 0; i < 4; ++i)
#pragma unroll
        for (int j = 0; j < 2; ++j)
#pragma unroll
            for (int k = 0; k < 16; ++k) acc[i][j][k] = 0;

    // prologue: tile0 fully (8 calls), tile1 all except uBe(1) (6 calls)
    stageA(0, 0, 0);     stageA(0, 128, 0);     // uAe(0)
    stageA(0, 64, 0);    stageA(0, 192, 0);     // uAo(0)
    stageB(0, 0, 0);     stageB(0, 64, 0);      // uBe(0)
    stageB(0, 128, 0);   stageB(0, 192, 0);     // uBo(0)
    stageA(1, 0, 128);   stageA(1, 128, 128);   // uAe(1)
    stageA(1, 64, 128);  stageA(1, 192, 128);   // uAo(1)
    stageB(1, 128, 128); stageB(1, 192, 128);   // uBo(1)
    asm volatile("s_waitcnt vmcnt(6)" ::: "memory");   // tile0's 8 landed
    __builtin_amdgcn_s_barrier();

    i32x4 aR[2][4], bR0[4], bR1[4];

    for (int t = 0; t < 8; ++t) {
        const int bi  = t & 1;
        const int kb1 = (t + 1) << 7;
        const int kb2 = (t + 2) << 7;

        // ---- phase 0 : Q(0,0) — read A-even (8) + B-nh0 (4); stage uBe(t+1)
#pragma unroll
        for (int mt = 0; mt < 2; ++mt)
#pragma unroll
            for (int ks = 0; ks < 4; ++ks) aR[mt][ks] = ldA32(bi, 0, mt, ks);
#pragma unroll
        for (int ks = 0; ks < 4; ++ks) bR0[ks] = ldB32(bi, 0, ks);
        if (t <= 6) { stageB(bi ^ 1, 0, kb1); stageB(bi ^ 1, 64, kb1); }
        PH32(0, 0, bR0)

        // ---- phase 1 : Q(0,1) — read B-nh1 (4); stage uAe(t+2)
#pragma unroll
        for (int ks = 0; ks < 4; ++ks) bR1[ks] = ldB32(bi, 1, ks);
        if (t <= 5) { stageA(bi, 0, kb2); stageA(bi, 128, kb2); }
        PH32(0, 1, bR1)

        // ---- phase 2 : Q(1,1) — read A-odd (8), keep bR1
#pragma unroll
        for (int mt = 0; mt < 2; ++mt)
#pragma unroll
            for (int ks = 0; ks < 4; ++ks) aR[mt][ks] = ldA32(bi, 1, mt, ks);
        PH32(1, 1, bR1)

        // ---- phase 3 : Q(1,0) — no reads (bR0 kept); stage uAo/uBo(t+2); counted vmcnt
        if (t <= 5) { stageA(bi, 64, kb2); stageA(bi, 192, kb2);
                      stageB(bi, 128, kb2); stageB(bi, 192, kb2); }
        if (t < 6) asm volatile("s_waitcnt vmcnt(6)" ::: "memory");
        else       asm volatile("s_waitcnt vmcnt(0)" ::: "memory");
        PH32(1, 0, bR0)
    }

    // ---- epilogue: 32x32 C layout: col=lane&31, row=(reg&3)+8*(reg>>2)+4*(lane>>5)
    const int colb = tn * 256 + wn * 64 + l31;
    const int rowb = tm * 256 + wm * 128 + 4 * l5;
#pragma unroll
    for (int mi = 0; mi < 4; ++mi) {
        float fr[16];
#pragma unroll
        for (int r = 0; r < 16; ++r)
            fr[r] = fact[rowb + mi * 32 + (r & 3) + 8 * (r >> 2)];
#pragma unroll
        for (int ni = 0; ni < 2; ++ni) {
            int c = colb + ni * 32;
            float bv = bias[c];
#pragma unroll
            for (int r = 0; r < 16; ++r) {
                int row = rowb + mi * 32 + (r & 3) + 8 * (r >> 2);
                out[(size_t)row * 1024 + c] = (float)acc[mi][ni][r] * fr[r] + bv;
            }
        }
    }
}

extern "C" void kernel_launch(void* const* d_in, const int* in_sizes, int n_in,
                              void* d_out, int out_size, void* d_ws, size_t ws_size,
                              hipStream_t stream) {
    const float* x    = (const float*)d_in[0];
    const float* w    = (const float*)d_in[1];
    const float* bias = (const float*)d_in[2];
    float* out = (float*)d_out;
    char* ws = (char*)d_ws;

    double* partials = (double*)ws;
    double* scale_d  = (double*)(ws + WS_SCALED);
    float*  scale_f  = (float*)(ws + WS_SCALEF);
    float*  fact     = (float*)(ws + WS_FACT);
    int8_t* xq       = (int8_t*)(ws + WS_XQ);
    int8_t* qw       = (int8_t*)(ws + WS_QW);

    k_wabs_partial<<<256, 256, 0, stream>>>(w, partials);
    k_scale<<<1, 256, 0, stream>>>(partials, scale_d, scale_f);
    k_wquant<<<512, 256, 0, stream>>>(w, scale_d, qw);
    k_aquant<<<8192, 256, 0, stream>>>(x, scale_f, xq, fact);
    k_gemm3<<<512, 512, 0, stream>>>(xq, qw, fact, bias, out);
}

// Round 4
// 92.163 us; speedup vs baseline: 1.0799x; 1.0799x over previous
//
#include <hip/hip_runtime.h>
#include <stdint.h>

using i32x4  = __attribute__((ext_vector_type(4))) int;
using i32x16 = __attribute__((ext_vector_type(16))) int;

// ---------------- ws layout ----------------
#define WS_SCALED   2048
#define WS_SCALEF   2056
#define WS_FACT     4096
#define WS_XQ       (1u << 20)
#define WS_QW       ((1u << 20) + (32u << 20))

// ---------------- kernel 1: fused aquant (blocks 0..8191) + wabs partials (8192..8447) ----
__device__ inline int q8pack(float4 f, float as) {
    int a = (int)fminf(fmaxf(rintf(f.x * as), -128.0f), 127.0f);
    int b = (int)fminf(fmaxf(rintf(f.y * as), -128.0f), 127.0f);
    int c = (int)fminf(fmaxf(rintf(f.z * as), -128.0f), 127.0f);
    int d = (int)fminf(fmaxf(rintf(f.w * as), -128.0f), 127.0f);
    return (a & 0xff) | ((b & 0xff) << 8) | ((c & 0xff) << 16) | ((d & 0xff) << 24);
}

__global__ __launch_bounds__(256) void k_fused1(const float* __restrict__ x,
                                                const float* __restrict__ w,
                                                int8_t* __restrict__ xq,
                                                float* __restrict__ fact,
                                                double* __restrict__ partials) {
    int t = threadIdx.x;
    if (blockIdx.x >= 8192) {
        // ---- wabs partial sums (deterministic, same order as before) ----
        int b = blockIdx.x - 8192;
        const float4* w4 = (const float4*)(w + b * 4096);
        double s = 0.0;
#pragma unroll
        for (int i = 0; i < 4; ++i) {
            float4 v = w4[i * 256 + t];
            s += (double)fabsf(v.x) + (double)fabsf(v.y) +
                 (double)fabsf(v.z) + (double)fabsf(v.w);
        }
#pragma unroll
        for (int off = 32; off > 0; off >>= 1) s += __shfl_down(s, off, 64);
        __shared__ double lds[4];
        if ((t & 63) == 0) lds[t >> 6] = s;
        __syncthreads();
        if (t == 0) partials[b] = ((lds[0] + lds[1]) + (lds[2] + lds[3]));
        return;
    }
    // ---- per-token int8 activation quant (scale deferred to GEMM epilogue) ----
    int wid = t >> 6;
    int lane = t & 63;
    int token = blockIdx.x * 4 + wid;
    const float* xr = x + (size_t)token * 1024;
    float4 v[4];
    float m = 0.0f;
#pragma unroll
    for (int c = 0; c < 4; ++c) {
        v[c] = *(const float4*)(xr + c * 256 + lane * 4);
        m = fmaxf(m, fmaxf(fmaxf(fabsf(v[c].x), fabsf(v[c].y)),
                           fmaxf(fabsf(v[c].z), fabsf(v[c].w))));
    }
#pragma unroll
    for (int off = 32; off > 0; off >>= 1) m = fmaxf(m, __shfl_xor(m, off, 64));
    m = fmaxf(m, 1e-5f);
    float as = 127.0f / m;
    int* xqo = (int*)xq;
#pragma unroll
    for (int c = 0; c < 4; ++c)
        xqo[token * 256 + c * 64 + lane] = q8pack(v[c], as);
    if (lane == 0) fact[token] = 1.0f / as;      // act_scale^-1 ; weight scale applied in epilogue
}

// ---------------- kernel 2: fused scale-reduce (per-block, redundant+deterministic) + wquant
__global__ __launch_bounds__(256) void k_fused2(const float* __restrict__ w,
                                                const double* __restrict__ partials,
                                                int8_t* __restrict__ qw,
                                                float* __restrict__ scale_f) {
    int t = threadIdx.x;
    // every block reduces the 256 partials in the exact same order -> identical scale
    double s = partials[t];
#pragma unroll
    for (int off = 32; off > 0; off >>= 1) s += __shfl_down(s, off, 64);
    __shared__ double lds[4];
    if ((t & 63) == 0) lds[t >> 6] = s;
    __syncthreads();
    __shared__ double sc_sh;
    if (t == 0) {
        double m = ((lds[0] + lds[1]) + (lds[2] + lds[3])) / 1048576.0;
        if (m < 1e-5) m = 1e-5;
        sc_sh = m;
        if (blockIdx.x == 0) *scale_f = (float)m;
    }
    __syncthreads();
    double half_s = 0.5 * sc_sh;

    int idx = blockIdx.x * 2048 + t * 8;
    float4 v0 = *(const float4*)(w + idx);
    float4 v1 = *(const float4*)(w + idx + 4);
    float f[8] = {v0.x, v0.y, v0.z, v0.w, v1.x, v1.y, v1.z, v1.w};
    union { char c[8]; int2 p; } u;
#pragma unroll
    for (int i = 0; i < 8; ++i) {
        char q = 0;
        if ((double)fabsf(f[i]) > half_s) q = (f[i] > 0.0f) ? 1 : -1;
        u.c[i] = q;
    }
    *(int2*)(qw + idx) = u.p;
}

// ---------------- kernel 3: i8 MFMA GEMM, 256x256 tile, 8-phase, 32x32x32 ----------------
__device__ __forceinline__ void gl_lds16(const void* g, void* l) {
    __builtin_amdgcn_global_load_lds((const __attribute__((address_space(1))) void*)g,
                                     (__attribute__((address_space(3))) void*)l, 16, 0, 0);
}

#define PH32(MH, NH, BRS) \
    __builtin_amdgcn_s_barrier(); \
    asm volatile("s_waitcnt lgkmcnt(0)" ::: "memory"); \
    __builtin_amdgcn_sched_barrier(0); \
    __builtin_amdgcn_s_setprio(1); \
    _Pragma("unroll") \
    for (int ks = 0; ks < 4; ++ks) \
    _Pragma("unroll") \
    for (int mt = 0; mt < 2; ++mt) \
        acc[MH*2+mt][NH] = __builtin_amdgcn_mfma_i32_32x32x32_i8( \
            aR[mt][ks], BRS[ks], acc[MH*2+mt][NH], 0, 0, 0); \
    __builtin_amdgcn_s_setprio(0); \
    __builtin_amdgcn_s_barrier();

__global__ __launch_bounds__(512, 2) void k_gemm3(const int8_t* __restrict__ A,
                                                  const int8_t* __restrict__ B,
                                                  const float* __restrict__ fact,
                                                  const float* __restrict__ scale_f,
                                                  const float* __restrict__ bias,
                                                  float* __restrict__ out) {
    __shared__ int8_t As[2][256 * 128];
    __shared__ int8_t Bs[2][256 * 128];
    const int tid  = threadIdx.x;
    const int lane = tid & 63;
    const int wid  = tid >> 6;
    const int wm   = wid >> 2;
    const int wn   = wid & 3;
    const int l31  = lane & 31;
    const int l5   = lane >> 5;

    int bid = blockIdx.x;
    int swz = (bid & 7) * 64 + (bid >> 3);
    int tm = swz >> 2;
    int tn = swz & 3;

    const int8_t* Ag = A + (size_t)tm * 256 * 1024;
    const int8_t* Bg = B + (size_t)tn * 256 * 1024;

    const int sr  = tid >> 3;
    const int ssl = tid & 7;

    auto stageA = [&](int bi, int r0, int kb) {
        int pr = r0 + sr;
        gl_lds16(Ag + (size_t)pr * 1024 + kb + ((ssl ^ (pr & 7)) << 4),
                 &As[bi][r0 * 128 + tid * 16]);
    };
    auto stageB = [&](int bi, int r0, int kb) {
        int pr = r0 + sr;
        int br = ((pr & 127) >> 5) * 64 + ((pr >> 7) << 5) + (pr & 31);
        gl_lds16(Bg + (size_t)br * 1024 + kb + ((ssl ^ (pr & 7)) << 4),
                 &Bs[bi][r0 * 128 + tid * 16]);
    };
    auto ldA32 = [&](int bi, int mh, int mt, int ks) -> i32x4 {
        int r  = wm * 128 + mh * 64 + mt * 32 + l31;
        int sl = ((ks << 1) + l5) ^ (r & 7);
        return *(const i32x4*)&As[bi][r * 128 + (sl << 4)];
    };
    auto ldB32 = [&](int bi, int nh, int ks) -> i32x4 {
        int pr = nh * 128 + wn * 32 + l31;
        int sl = ((ks << 1) + l5) ^ (pr & 7);
        return *(const i32x4*)&Bs[bi][pr * 128 + (sl << 4)];
    };

    i32x16 acc[4][2];
#pragma unroll
    for (int i = 0; i < 4; ++i)
#pragma unroll
        for (int j = 0; j < 2; ++j)
#pragma unroll
            for (int k = 0; k < 16; ++k) acc[i][j][k] = 0;

    stageA(0, 0, 0);     stageA(0, 128, 0);
    stageA(0, 64, 0);    stageA(0, 192, 0);
    stageB(0, 0, 0);     stageB(0, 64, 0);
    stageB(0, 128, 0);   stageB(0, 192, 0);
    stageA(1, 0, 128);   stageA(1, 128, 128);
    stageA(1, 64, 128);  stageA(1, 192, 128);
    stageB(1, 128, 128); stageB(1, 192, 128);
    asm volatile("s_waitcnt vmcnt(6)" ::: "memory");
    __builtin_amdgcn_s_barrier();

    i32x4 aR[2][4], bR0[4], bR1[4];

    for (int t = 0; t < 8; ++t) {
        const int bi  = t & 1;
        const int kb1 = (t + 1) << 7;
        const int kb2 = (t + 2) << 7;

#pragma unroll
        for (int mt = 0; mt < 2; ++mt)
#pragma unroll
            for (int ks = 0; ks < 4; ++ks) aR[mt][ks] = ldA32(bi, 0, mt, ks);
#pragma unroll
        for (int ks = 0; ks < 4; ++ks) bR0[ks] = ldB32(bi, 0, ks);
        if (t <= 6) { stageB(bi ^ 1, 0, kb1); stageB(bi ^ 1, 64, kb1); }
        PH32(0, 0, bR0)

#pragma unroll
        for (int ks = 0; ks < 4; ++ks) bR1[ks] = ldB32(bi, 1, ks);
        if (t <= 5) { stageA(bi, 0, kb2); stageA(bi, 128, kb2); }
        PH32(0, 1, bR1)

#pragma unroll
        for (int mt = 0; mt < 2; ++mt)
#pragma unroll
            for (int ks = 0; ks < 4; ++ks) aR[mt][ks] = ldA32(bi, 1, mt, ks);
        PH32(1, 1, bR1)

        if (t <= 5) { stageA(bi, 64, kb2); stageA(bi, 192, kb2);
                      stageB(bi, 128, kb2); stageB(bi, 192, kb2); }
        if (t < 6) asm volatile("s_waitcnt vmcnt(6)" ::: "memory");
        else       asm volatile("s_waitcnt vmcnt(0)" ::: "memory");
        PH32(1, 0, bR0)
    }

    // ---- epilogue: fr = scale * fact[row] ----
    const float sc = *scale_f;
    const int colb = tn * 256 + wn * 64 + l31;
    const int rowb = tm * 256 + wm * 128 + 4 * l5;
#pragma unroll
    for (int mi = 0; mi < 4; ++mi) {
        float fr[16];
#pragma unroll
        for (int r = 0; r < 16; ++r)
            fr[r] = sc * fact[rowb + mi * 32 + (r & 3) + 8 * (r >> 2)];
#pragma unroll
        for (int ni = 0; ni < 2; ++ni) {
            int c = colb + ni * 32;
            float bv = bias[c];
#pragma unroll
            for (int r = 0; r < 16; ++r) {
                int row = rowb + mi * 32 + (r & 3) + 8 * (r >> 2);
                out[(size_t)row * 1024 + c] = (float)acc[mi][ni][r] * fr[r] + bv;
            }
        }
    }
}

extern "C" void kernel_launch(void* const* d_in, const int* in_sizes, int n_in,
                              void* d_out, int out_size, void* d_ws, size_t ws_size,
                              hipStream_t stream) {
    const float* x    = (const float*)d_in[0];
    const float* w    = (const float*)d_in[1];
    const float* bias = (const float*)d_in[2];
    float* out = (float*)d_out;
    char* ws = (char*)d_ws;

    double* partials = (double*)ws;
    float*  scale_f  = (float*)(ws + WS_SCALEF);
    float*  fact     = (float*)(ws + WS_FACT);
    int8_t* xq       = (int8_t*)(ws + WS_XQ);
    int8_t* qw       = (int8_t*)(ws + WS_QW);

    k_fused1<<<8448, 256, 0, stream>>>(x, w, xq, fact, partials);
    k_fused2<<<512, 256, 0, stream>>>(w, partials, qw, scale_f);
    k_gemm3<<<512, 512, 0, stream>>>(xq, qw, fact, scale_f, bias, out);
}